// Round 2
// baseline (193.001 us; speedup 1.0000x reference)
//
#include <hip/hip_runtime.h>

#define EMB 2048
#define NC 4
#define NROWS 16384
#define SCALE_S 16.0f

// One wave per row-group. Block = 256 threads = 4 waves.
// W (4 x 2048 fp32 = 32 KB) lives entirely in REGISTERS:
//   per lane: w[c][j] = W[c][ (j*64+lane)*4 .. +3 ]  -> 32 float4 = 128 VGPRs.
// No LDS, no __syncthreads. Rows are software-pipelined (prefetch next row's
// 8 float4 while computing the current row's dot products).
#define ROWS_PER_WAVE 8
#define WAVES_PER_BLOCK 4

__global__ __launch_bounds__(256, 2) void binary_head_kernel(
    const float* __restrict__ fea,
    const float* __restrict__ W,
    const float* __restrict__ bias,
    float* __restrict__ out)
{
    const int tid  = threadIdx.x;
    const int wave = tid >> 6;
    const int lane = tid & 63;

    // ---- Load W into registers (once per wave; all waves hit L2/L1) ----
    const float4* W4 = (const float4*)W;
    float4 w[NC][8];
#pragma unroll
    for (int c = 0; c < NC; ++c) {
#pragma unroll
        for (int j = 0; j < 8; ++j) {
            w[c][j] = W4[c * (EMB / 4) + j * 64 + lane];
        }
    }

    const float bval = bias[lane & (NC - 1)];

    const int gwave = blockIdx.x * WAVES_PER_BLOCK + wave;
    const int row0  = gwave * ROWS_PER_WAVE;
    const float4* fea4 = (const float4*)fea;

    // ---- Software pipeline: prefetch row0 ----
    float4 xa[8], xb[8];
    {
        const float4* frow = fea4 + (size_t)row0 * (EMB / 4);
#pragma unroll
        for (int j = 0; j < 8; ++j) xa[j] = frow[j * 64 + lane];
    }

#pragma unroll
    for (int r = 0; r < ROWS_PER_WAVE; ++r) {
        // Prefetch next row while we compute the current one.
        // Clamp so the last wave doesn't read past the end (result unused).
        {
            int pr = row0 + r + 1;
            if (pr > NROWS - 1) pr = NROWS - 1;
            const float4* fn = fea4 + (size_t)pr * (EMB / 4);
#pragma unroll
            for (int j = 0; j < 8; ++j) xb[j] = fn[j * 64 + lane];
        }

        float ss = 0.0f, d0 = 0.0f, d1 = 0.0f, d2 = 0.0f, d3 = 0.0f;
#pragma unroll
        for (int j = 0; j < 8; ++j) {
            const float4 v = xa[j];
            ss += v.x * v.x + v.y * v.y + v.z * v.z + v.w * v.w;
            d0 += v.x * w[0][j].x + v.y * w[0][j].y + v.z * w[0][j].z + v.w * w[0][j].w;
            d1 += v.x * w[1][j].x + v.y * w[1][j].y + v.z * w[1][j].z + v.w * w[1][j].w;
            d2 += v.x * w[2][j].x + v.y * w[2][j].y + v.z * w[2][j].z + v.w * w[2][j].w;
            d3 += v.x * w[3][j].x + v.y * w[3][j].y + v.z * w[3][j].z + v.w * w[3][j].w;
        }

        // 64-lane butterfly reduction of the 5 partials.
#pragma unroll
        for (int m = 1; m < 64; m <<= 1) {
            ss += __shfl_xor(ss, m, 64);
            d0 += __shfl_xor(d0, m, 64);
            d1 += __shfl_xor(d1, m, 64);
            d2 += __shfl_xor(d2, m, 64);
            d3 += __shfl_xor(d3, m, 64);
        }

        if (lane < NC) {
            const float d = (lane == 0) ? d0 : (lane == 1) ? d1 : (lane == 2) ? d2 : d3;
            out[(row0 + r) * NC + lane] = (d * rsqrtf(ss) + bval) * SCALE_S;
        }

        // Rotate pipeline buffers (unrolled loop -> compiler renames, no movs).
#pragma unroll
        for (int j = 0; j < 8; ++j) xa[j] = xb[j];
    }
}

extern "C" void kernel_launch(void* const* d_in, const int* in_sizes, int n_in,
                              void* d_out, int out_size, void* d_ws, size_t ws_size,
                              hipStream_t stream) {
    const float* fea  = (const float*)d_in[0];
    const float* W    = (const float*)d_in[1];
    const float* bias = (const float*)d_in[2];
    float* out = (float*)d_out;

    const int grid = NROWS / (ROWS_PER_WAVE * WAVES_PER_BLOCK);  // 512
    binary_head_kernel<<<grid, 256, 0, stream>>>(fea, W, bias, out);
}